// Round 1
// baseline (449.378 us; speedup 1.0000x reference)
//
#include <hip/hip_runtime.h>

#define S_LEN 2048
#define E_DIM 1024
#define NH 16
#define HD 128
#define NB 2
#define NPAIR (NH*NB)

typedef __attribute__((ext_vector_type(4))) float f32x4;
typedef __attribute__((ext_vector_type(8))) short bf16x8;

__device__ __forceinline__ unsigned short f2bf(float f) {
    unsigned u = __builtin_bit_cast(unsigned, f);
    u += 0x7fffu + ((u >> 16) & 1u);
    return (unsigned short)(u >> 16);
}
__device__ __forceinline__ float bf2f(unsigned short h) {
    unsigned u = ((unsigned)h) << 16;
    return __builtin_bit_cast(float, u);
}

__device__ __forceinline__ void gl_lds16(const unsigned short* g, unsigned short* l) {
    __builtin_amdgcn_global_load_lds((__attribute__((address_space(1))) void*)g,
                                     (__attribute__((address_space(3))) void*)l,
                                     16, 0, 0);
}

// C[M,N] = A[M,K] @ B[N,K]^T (+bias_row +bias_col), bf16 in, fp32 acc.
// grid = (N/128, M/128, Z). z -> (zh = z/zdiv, zl = z%zdiv); per-operand offsets
// off = zh*sh + zl*sl (elements). OF32: 1 = fp32 out, 0 = bf16 out.
template<int OF32>
__global__ __launch_bounds__(256, 2) void gemm_bt(
    const unsigned short* __restrict__ A, const unsigned short* __restrict__ B,
    void* __restrict__ C,
    const float* __restrict__ brow, const float* __restrict__ bcol,
    int K, int lda, int ldb, int ldc, int zdiv,
    long long a_sh, long long a_sl, long long b_sh, long long b_sl,
    long long c_sh, long long c_sl, int brs, int bcs)
{
    __shared__ unsigned short As[128*64];
    __shared__ unsigned short Bs[128*64];
    const int z = blockIdx.z;
    const int zh = z / zdiv, zl = z % zdiv;
    A += (long long)zh*a_sh + (long long)zl*a_sl;
    B += (long long)zh*b_sh + (long long)zl*b_sl;
    const long long coff = (long long)zh*c_sh + (long long)zl*c_sl;
    const int bm = blockIdx.y, bn = blockIdx.x;
    const int tid = threadIdx.x, wid = tid >> 6, lane = tid & 63;
    // staging: each wave fills 32 rows of A-tile and B-tile; 4 issues of
    // 1KB (64 lanes x 16B). LDS dest is linear (wave base + lane*16B);
    // the XOR chunk swizzle is applied on the GLOBAL source (rule #21),
    // and un-applied on the ds_read side below.
    const int l3 = lane >> 3;              // row within 8-row group
    const int cg = (lane & 7) ^ l3;        // pre-swizzled global 16B-chunk
    const unsigned short* Ag = A + (long long)(bm*128 + wid*32 + l3)*lda + cg*8;
    const unsigned short* Bg = B + (long long)(bn*128 + wid*32 + l3)*ldb + cg*8;

    f32x4 acc[4][4];
    #pragma unroll
    for (int m = 0; m < 4; ++m)
        #pragma unroll
        for (int n = 0; n < 4; ++n)
            #pragma unroll
            for (int j = 0; j < 4; ++j) acc[m][n][j] = 0.f;

    const int r0 = lane & 15, q = lane >> 4;
    const int wr = (wid >> 1) * 64, wc = (wid & 1) * 64;

    for (int kt = 0; kt < K; kt += 64) {
        #pragma unroll
        for (int i = 0; i < 4; ++i) {
            gl_lds16(Ag + (long long)(i*8)*lda + kt, &As[(wid*32 + i*8)*64]);
            gl_lds16(Bg + (long long)(i*8)*ldb + kt, &Bs[(wid*32 + i*8)*64]);
        }
        __syncthreads();   // drains vmcnt before reads
        #pragma unroll
        for (int ks = 0; ks < 2; ++ks) {
            bf16x8 av[4], bv[4];
            #pragma unroll
            for (int m = 0; m < 4; ++m) {
                const int ra = wr + m*16 + r0;
                av[m] = *(const bf16x8*)&As[ra*64 + (((ks*4 + q) ^ (ra & 7)) << 3)];
                const int rb = wc + m*16 + r0;
                bv[m] = *(const bf16x8*)&Bs[rb*64 + (((ks*4 + q) ^ (rb & 7)) << 3)];
            }
            #pragma unroll
            for (int m = 0; m < 4; ++m)
                #pragma unroll
                for (int n = 0; n < 4; ++n)
                    acc[m][n] = __builtin_amdgcn_mfma_f32_16x16x32_bf16(
                        av[m], bv[n], acc[m][n], 0, 0, 0);
        }
        __syncthreads();
    }

    // epilogue: C/D layout col = lane&15, row = (lane>>4)*4 + j (m89/m91)
    const int rq = lane >> 4;
    const bool has_br = (brow != nullptr), has_bc = (bcol != nullptr);
    #pragma unroll
    for (int m = 0; m < 4; ++m) {
        #pragma unroll
        for (int n = 0; n < 4; ++n) {
            const int gcol = bn*128 + wc + n*16 + r0;
            float cb = has_bc ? bcol[(long long)bcs*zh + gcol] : 0.f;
            #pragma unroll
            for (int j = 0; j < 4; ++j) {
                const int grow = bm*128 + wr + m*16 + rq*4 + j;
                float v = acc[m][n][j] + cb;
                if (has_br) v += brow[(long long)brs*zh + grow];
                const long long idx = coff + (long long)grow*ldc + gcol;
                if (OF32) ((float*)C)[idx] = v;
                else      ((unsigned short*)C)[idx] = f2bf(v);
            }
        }
    }
}

// row softmax, in place, bf16. grid = (S_LEN rows, nPairs), 256 threads/row.
__global__ __launch_bounds__(256) void softmax_rows(unsigned short* __restrict__ P)
{
    const long long base = ((long long)blockIdx.y * S_LEN + blockIdx.x) * S_LEN;
    const int tid = threadIdx.x;
    uint4 raw = *(const uint4*)&P[base + tid*8];
    unsigned short* us = (unsigned short*)&raw;
    float v[8];
    float mx = -3.0e38f;
    #pragma unroll
    for (int j = 0; j < 8; ++j) { v[j] = bf2f(us[j]); mx = fmaxf(mx, v[j]); }
    #pragma unroll
    for (int o = 32; o > 0; o >>= 1) mx = fmaxf(mx, __shfl_xor(mx, o, 64));
    __shared__ float red[8];
    const int wid = tid >> 6, lane = tid & 63;
    if (lane == 0) red[wid] = mx;
    __syncthreads();
    mx = fmaxf(fmaxf(red[0], red[1]), fmaxf(red[2], red[3]));
    float s = 0.f;
    #pragma unroll
    for (int j = 0; j < 8; ++j) { v[j] = __expf(v[j] - mx); s += v[j]; }
    #pragma unroll
    for (int o = 32; o > 0; o >>= 1) s += __shfl_xor(s, o, 64);
    if (lane == 0) red[4 + wid] = s;
    __syncthreads();
    s = (red[4] + red[5]) + (red[6] + red[7]);
    const float inv = 1.f / s;
    #pragma unroll
    for (int j = 0; j < 8; ++j) us[j] = f2bf(v[j] * inv);
    *(uint4*)&P[base + tid*8] = raw;
}

// x (NB,E,S) f32 -> xT (NB,S,E) bf16
__global__ __launch_bounds__(256) void transpose_conv(
    const float* __restrict__ x, unsigned short* __restrict__ xT)
{
    __shared__ float t[32][33];
    const int n = blockIdx.z;
    const int e0 = blockIdx.y * 32, s0 = blockIdx.x * 32;
    const int tx = threadIdx.x & 31, ty = threadIdx.x >> 5;
    #pragma unroll
    for (int i = 0; i < 4; ++i) {
        const int e = ty + i*8;
        t[e][tx] = x[((long long)n*E_DIM + e0 + e)*S_LEN + s0 + tx];
    }
    __syncthreads();
    #pragma unroll
    for (int i = 0; i < 4; ++i) {
        const int s = ty + i*8;
        xT[((long long)n*S_LEN + s0 + s)*E_DIM + e0 + tx] = f2bf(t[tx][s]);
    }
}

__global__ __launch_bounds__(256) void conv_bf16(
    const float* __restrict__ in, unsigned short* __restrict__ out, int n8)
{
    const int i = blockIdx.x * 256 + threadIdx.x;
    if (i >= n8) return;
    const float4 a = ((const float4*)in)[2*i];
    const float4 b = ((const float4*)in)[2*i + 1];
    unsigned short u[8] = {f2bf(a.x), f2bf(a.y), f2bf(a.z), f2bf(a.w),
                           f2bf(b.x), f2bf(b.y), f2bf(b.z), f2bf(b.w)};
    ((uint4*)out)[i] = *(const uint4*)u;
}

extern "C" void kernel_launch(void* const* d_in, const int* in_sizes, int n_in,
                              void* d_out, int out_size, void* d_ws, size_t ws_size,
                              hipStream_t stream)
{
    const float* x   = (const float*)d_in[0];
    const float* W_r = (const float*)d_in[1];
    const float* b_r = (const float*)d_in[2];
    const float* Wq  = (const float*)d_in[3];
    const float* bq  = (const float*)d_in[4];
    const float* Wk  = (const float*)d_in[5];
    const float* bk  = (const float*)d_in[6];
    const float* Wv  = (const float*)d_in[7];
    const float* bv  = (const float*)d_in[8];
    const float* Wo  = (const float*)d_in[9];
    const float* bo  = (const float*)d_in[10];
    float* out = (float*)d_out;
    (void)in_sizes; (void)n_in; (void)out_size;

    char* w = (char*)d_ws;
    size_t off = 0;
    auto take = [&](size_t bytes) -> unsigned short* {
        unsigned short* p = (unsigned short*)(w + off);
        off = (off + bytes + 255) & ~(size_t)255;
        return p;
    };
    unsigned short* Wr_b = take((size_t)S_LEN*E_DIM*2);
    unsigned short* xT_b = take((size_t)NB*S_LEN*E_DIM*2);
    unsigned short* Wq_b = take((size_t)NH*HD*HD*2);
    unsigned short* Wk_b = take((size_t)NH*HD*HD*2);
    unsigned short* Wv_b = take((size_t)NH*HD*HD*2);
    unsigned short* Wo_b = take((size_t)E_DIM*S_LEN*2);
    unsigned short* Rd_b = take((size_t)NB*S_LEN*S_LEN*2);   // reduced, bf16 (n,j,s)
    unsigned short* Q_b  = take((size_t)NPAIR*S_LEN*HD*2);   // (h,n,s,k)
    unsigned short* K_b  = take((size_t)NPAIR*S_LEN*HD*2);   // (h,n,s,k)
    unsigned short* Vt_b = take((size_t)NPAIR*HD*S_LEN*2);   // (h,n,d,t)  V^T
    unsigned short* O_b  = take((size_t)NPAIR*S_LEN*HD*2);   // (h,n,s,d) == reshape view
    int nch = NPAIR;     // score pairs per chunk, shrink to fit workspace
    while (nch > 1 && off + (size_t)nch*S_LEN*S_LEN*2 > ws_size) nch >>= 1;
    unsigned short* P_b = take((size_t)nch*S_LEN*S_LEN*2);

    // ---- convert weights / transpose x to bf16 ----
    conv_bf16<<<dim3((S_LEN*E_DIM/8 + 255)/256), 256, 0, stream>>>(W_r, Wr_b, S_LEN*E_DIM/8);
    conv_bf16<<<dim3((NH*HD*HD/8 + 255)/256), 256, 0, stream>>>(Wq, Wq_b, NH*HD*HD/8);
    conv_bf16<<<dim3((NH*HD*HD/8 + 255)/256), 256, 0, stream>>>(Wk, Wk_b, NH*HD*HD/8);
    conv_bf16<<<dim3((NH*HD*HD/8 + 255)/256), 256, 0, stream>>>(Wv, Wv_b, NH*HD*HD/8);
    conv_bf16<<<dim3((E_DIM*S_LEN/8 + 255)/256), 256, 0, stream>>>(Wo, Wo_b, E_DIM*S_LEN/8);
    transpose_conv<<<dim3(S_LEN/32, E_DIM/32, NB), 256, 0, stream>>>(x, xT_b);

    // ---- reduced[n,j,s] = W_r @ x[n] + b_r[j] ----
    gemm_bt<0><<<dim3(S_LEN/128, S_LEN/128, NB), 256, 0, stream>>>(
        Wr_b, xT_b, Rd_b, b_r, nullptr,
        E_DIM, E_DIM, E_DIM, S_LEN, 1,
        0LL, 0LL, (long long)S_LEN*E_DIM, 0LL, (long long)S_LEN*S_LEN, 0LL, 0, 0);

    // ---- Q/K projections: z=(h,n), A = reduced head-slice, B = W ----
    gemm_bt<0><<<dim3(HD/128, S_LEN/128, NPAIR), 256, 0, stream>>>(
        Rd_b, Wq_b, Q_b, nullptr, bq,
        HD, S_LEN, HD, HD, NB,
        128LL, (long long)S_LEN*S_LEN, (long long)HD*HD, 0LL,
        (long long)NB*S_LEN*HD, (long long)S_LEN*HD, 0, HD);
    gemm_bt<0><<<dim3(HD/128, S_LEN/128, NPAIR), 256, 0, stream>>>(
        Rd_b, Wk_b, K_b, nullptr, bk,
        HD, S_LEN, HD, HD, NB,
        128LL, (long long)S_LEN*S_LEN, (long long)HD*HD, 0LL,
        (long long)NB*S_LEN*HD, (long long)S_LEN*HD, 0, HD);
    // ---- V, produced transposed: Vt = Wv_h @ R^T ----
    gemm_bt<0><<<dim3(S_LEN/128, HD/128, NPAIR), 256, 0, stream>>>(
        Wv_b, Rd_b, Vt_b, bv, nullptr,
        HD, HD, S_LEN, S_LEN, NB,
        (long long)HD*HD, 0LL, 128LL, (long long)S_LEN*S_LEN,
        (long long)NB*HD*S_LEN, (long long)HD*S_LEN, HD, 0);

    // ---- attention, chunked over (h,n) pairs ----
    for (int cb = 0; cb < NPAIR; cb += nch) {
        gemm_bt<0><<<dim3(S_LEN/128, S_LEN/128, nch), 256, 0, stream>>>(
            Q_b + (size_t)cb*S_LEN*HD, K_b + (size_t)cb*S_LEN*HD, P_b,
            nullptr, nullptr,
            HD, HD, HD, S_LEN, 1,
            (long long)S_LEN*HD, 0LL, (long long)S_LEN*HD, 0LL,
            (long long)S_LEN*S_LEN, 0LL, 0, 0);
        softmax_rows<<<dim3(S_LEN, nch), 256, 0, stream>>>(P_b);
        gemm_bt<0><<<dim3(HD/128, S_LEN/128, nch), 256, 0, stream>>>(
            P_b, Vt_b + (size_t)cb*HD*S_LEN, O_b + (size_t)cb*S_LEN*HD,
            nullptr, nullptr,
            S_LEN, S_LEN, S_LEN, HD, 1,
            (long long)S_LEN*S_LEN, 0LL, (long long)HD*S_LEN, 0LL,
            (long long)S_LEN*HD, 0LL, 0, 0);
    }

    // ---- out[n] = O_resh[n] @ Wo^T + bo ; O_b reinterpreted (N,S,H*HD) ----
    gemm_bt<1><<<dim3(E_DIM/128, S_LEN/128, NB), 256, 0, stream>>>(
        O_b, Wo_b, out, nullptr, bo,
        S_LEN, S_LEN, S_LEN, E_DIM, 1,
        (long long)S_LEN*S_LEN, 0LL, 0LL, 0LL, (long long)S_LEN*E_DIM, 0LL, 0, 0);
}

// Round 2
// 440.482 us; speedup vs baseline: 1.0202x; 1.0202x over previous
//
#include <hip/hip_runtime.h>

#define S_LEN 2048
#define E_DIM 1024
#define NH 16
#define HD 128
#define NB 2
#define NPAIR (NH*NB)

typedef __attribute__((ext_vector_type(4))) float f32x4;
typedef __attribute__((ext_vector_type(8))) short bf16x8;

__device__ __forceinline__ unsigned short f2bf(float f) {
    unsigned u = __builtin_bit_cast(unsigned, f);
    u += 0x7fffu + ((u >> 16) & 1u);
    return (unsigned short)(u >> 16);
}
__device__ __forceinline__ float bf2f(unsigned short h) {
    unsigned u = ((unsigned)h) << 16;
    return __builtin_bit_cast(float, u);
}

__device__ __forceinline__ void gl_lds16(const unsigned short* g, unsigned short* l) {
    __builtin_amdgcn_global_load_lds((__attribute__((address_space(1))) void*)g,
                                     (__attribute__((address_space(3))) void*)l,
                                     16, 0, 0);
}

// C[M,N] = A[M,K] @ B[N,K]^T (+bias_row +bias_col), bf16 in, fp32 acc.
// 2-phase double-buffered (stage t+1 before compute t, ONE barrier/iter).
// SWZ=1: XCD-chunked block swizzle on the full flattened grid (needs nwg%8==0).
template<int OF32, int SWZ>
__global__ __launch_bounds__(256, 2) void gemm_bt(
    const unsigned short* __restrict__ A, const unsigned short* __restrict__ B,
    void* __restrict__ C,
    const float* __restrict__ brow, const float* __restrict__ bcol,
    int K, int lda, int ldb, int ldc, int zdiv,
    long long a_sh, long long a_sl, long long b_sh, long long b_sl,
    long long c_sh, long long c_sl, int brs, int bcs)
{
    __shared__ unsigned short As[2][128*64];
    __shared__ unsigned short Bs[2][128*64];
    int bm, bn, z;
    if (SWZ) {
        const int gx = gridDim.x, gy = gridDim.y;
        const int nxy = gx * gy;
        const int nwg = nxy * gridDim.z;
        const int flat = (blockIdx.z*gy + blockIdx.y)*gx + blockIdx.x;
        const int id2 = (flat & 7)*(nwg >> 3) + (flat >> 3);  // XCD c -> contiguous run
        z = id2 / nxy; const int r = id2 % nxy; bm = r / gx; bn = r % gx;
    } else { bm = blockIdx.y; bn = blockIdx.x; z = blockIdx.z; }
    const int zh = z / zdiv, zl = z % zdiv;
    A += (long long)zh*a_sh + (long long)zl*a_sl;
    B += (long long)zh*b_sh + (long long)zl*b_sl;
    const long long coff = (long long)zh*c_sh + (long long)zl*c_sl;
    const int tid = threadIdx.x, wid = tid >> 6, lane = tid & 63;
    // staging: wave fills 32 rows each of A/B tile. LDS dest linear; XOR chunk
    // swizzle applied on the GLOBAL source (rule #21), un-applied on ds_read.
    const int l3 = lane >> 3;
    const int cg = (lane & 7) ^ l3;
    const unsigned short* Ag = A + (long long)(bm*128 + wid*32 + l3)*lda + cg*8;
    const unsigned short* Bg = B + (long long)(bn*128 + wid*32 + l3)*ldb + cg*8;

    f32x4 acc[4][4];
    #pragma unroll
    for (int m = 0; m < 4; ++m)
        #pragma unroll
        for (int n = 0; n < 4; ++n)
            #pragma unroll
            for (int j = 0; j < 4; ++j) acc[m][n][j] = 0.f;

    const int r0 = lane & 15, q = lane >> 4;
    const int wr = (wid >> 1) * 64, wc = (wid & 1) * 64;

    auto stage = [&](int buf, int kt) {
        unsigned short* as = &As[buf][wid*32*64];
        unsigned short* bs = &Bs[buf][wid*32*64];
        #pragma unroll
        for (int i = 0; i < 4; ++i) {
            gl_lds16(Ag + (long long)(i*8)*lda + kt, as + i*8*64);
            gl_lds16(Bg + (long long)(i*8)*ldb + kt, bs + i*8*64);
        }
    };

    const int nt = K >> 6;
    stage(0, 0);
    __syncthreads();
    int cur = 0;
    for (int t = 0; t < nt; ++t) {
        if (t + 1 < nt) stage(cur ^ 1, (t + 1) << 6);   // loads fly during MFMA
        #pragma unroll
        for (int ks = 0; ks < 2; ++ks) {
            bf16x8 av[4], bv[4];
            #pragma unroll
            for (int m = 0; m < 4; ++m) {
                const int ra = wr + m*16 + r0;
                av[m] = *(const bf16x8*)&As[cur][ra*64 + (((ks*4 + q) ^ (ra & 7)) << 3)];
                const int rb = wc + m*16 + r0;
                bv[m] = *(const bf16x8*)&Bs[cur][rb*64 + (((ks*4 + q) ^ (rb & 7)) << 3)];
            }
            #pragma unroll
            for (int m = 0; m < 4; ++m)
                #pragma unroll
                for (int n = 0; n < 4; ++n)
                    acc[m][n] = __builtin_amdgcn_mfma_f32_16x16x32_bf16(
                        av[m], bv[n], acc[m][n], 0, 0, 0);
        }
        __syncthreads();   // drains this iter's stage(t+1) + WAR fence
        cur ^= 1;
    }

    const int rq = lane >> 4;
    const bool has_br = (brow != nullptr), has_bc = (bcol != nullptr);
    #pragma unroll
    for (int m = 0; m < 4; ++m) {
        #pragma unroll
        for (int n = 0; n < 4; ++n) {
            const int gcol = bn*128 + wc + n*16 + r0;
            float cb = has_bc ? bcol[(long long)bcs*zh + gcol] : 0.f;
            #pragma unroll
            for (int j = 0; j < 4; ++j) {
                const int grow = bm*128 + wr + m*16 + rq*4 + j;
                float v = acc[m][n][j] + cb;
                if (has_br) v += brow[(long long)brs*zh + grow];
                const long long idx = coff + (long long)grow*ldc + gcol;
                if (OF32) ((float*)C)[idx] = v;
                else      ((unsigned short*)C)[idx] = f2bf(v);
            }
        }
    }
}

// Fused flash attention: P = softmax(Q K^T), O = P V. No 1/sqrt(d) scaling.
// grid (S/128, NPAIR), 256 thr. Wave w owns 32 q-rows. K/V frags straight from
// global (L2-resident, 1MB/pair); P transposed via 4KB/wave swizzled LDS.
__global__ __launch_bounds__(256, 2) void flash_attn(
    const unsigned short* __restrict__ Q,    // (pair, s, d)
    const unsigned short* __restrict__ Kb,   // (pair, s, d)
    const unsigned short* __restrict__ Vt,   // (pair, d, s)
    unsigned short* __restrict__ O)          // (pair, s, d)
{
    __shared__ unsigned short Plds[4][32*64];
    // XCD swizzle: each XCD owns 4 whole pairs -> K/V stay in its L2
    const int flat = blockIdx.y * gridDim.x + blockIdx.x;   // nwg = 512
    const int id2 = (flat & 7)*64 + (flat >> 3);
    const int pair = id2 >> 4, qt = id2 & 15;
    const int tid = threadIdx.x, wid = tid >> 6, lane = tid & 63;
    const int r0 = lane & 15, q4 = lane >> 4;
    const long long base = (long long)pair * S_LEN * HD;
    const unsigned short* Qp = Q + base + (long long)(qt*128 + wid*32) * HD;
    const unsigned short* Kp = Kb + base;
    const unsigned short* Vp = Vt + base;    // [d][t]
    unsigned short* P = &Plds[wid][0];

    // Q fragments: row = qf*16 + r0, k-chunk = ks*32 + q4*8
    bf16x8 qfr[2][4];
    #pragma unroll
    for (int qf = 0; qf < 2; ++qf)
        #pragma unroll
        for (int ks = 0; ks < 4; ++ks)
            qfr[qf][ks] = *(const bf16x8*)&Qp[(qf*16 + r0)*HD + ks*32 + q4*8];

    f32x4 o_acc[2][8];
    #pragma unroll
    for (int qf = 0; qf < 2; ++qf)
        #pragma unroll
        for (int nf = 0; nf < 8; ++nf)
            #pragma unroll
            for (int j = 0; j < 4; ++j) o_acc[qf][nf][j] = 0.f;
    float m_[2] = {-3.0e38f, -3.0e38f}, l_[2] = {0.f, 0.f};

    for (int kv = 0; kv < S_LEN; kv += 64) {
        // S^T tile: mfma(K, Q) -> row=key, col=query(lane&15)
        f32x4 sacc[4][2];
        #pragma unroll
        for (int kf = 0; kf < 4; ++kf)
            #pragma unroll
            for (int qf = 0; qf < 2; ++qf)
                #pragma unroll
                for (int j = 0; j < 4; ++j) sacc[kf][qf][j] = 0.f;
        #pragma unroll
        for (int ks = 0; ks < 4; ++ks) {
            bf16x8 kfr[4];
            #pragma unroll
            for (int kf = 0; kf < 4; ++kf)
                kfr[kf] = *(const bf16x8*)&Kp[(long long)(kv + kf*16 + r0)*HD + ks*32 + q4*8];
            #pragma unroll
            for (int kf = 0; kf < 4; ++kf)
                #pragma unroll
                for (int qf = 0; qf < 2; ++qf)
                    sacc[kf][qf] = __builtin_amdgcn_mfma_f32_16x16x32_bf16(
                        kfr[kf], qfr[qf][ks], sacc[kf][qf], 0, 0, 0);
        }
        // online softmax; lane's column = query qf*16+r0; keys = kf*16+q4*4+j
        #pragma unroll
        for (int qf = 0; qf < 2; ++qf) {
            float tmax = -3.0e38f;
            #pragma unroll
            for (int kf = 0; kf < 4; ++kf)
                #pragma unroll
                for (int j = 0; j < 4; ++j) tmax = fmaxf(tmax, sacc[kf][qf][j]);
            tmax = fmaxf(tmax, __shfl_xor(tmax, 16));
            tmax = fmaxf(tmax, __shfl_xor(tmax, 32));
            const float mnew = fmaxf(m_[qf], tmax);
            const float scale = __expf(m_[qf] - mnew);
            float tsum = 0.f;
            #pragma unroll
            for (int kf = 0; kf < 4; ++kf)
                #pragma unroll
                for (int j = 0; j < 4; ++j) {
                    const float e = __expf(sacc[kf][qf][j] - mnew);
                    sacc[kf][qf][j] = e; tsum += e;
                }
            tsum += __shfl_xor(tsum, 16);
            tsum += __shfl_xor(tsum, 32);
            l_[qf] = l_[qf]*scale + tsum;
            m_[qf] = mnew;
            // rescale O: o row = qf*16 + q4*4 + j; its scale lives in lane r0=q4*4+j
            float sc[4];
            #pragma unroll
            for (int j = 0; j < 4; ++j) sc[j] = __shfl(scale, (q4*4 + j) | (lane & 48));
            #pragma unroll
            for (int nf = 0; nf < 8; ++nf)
                #pragma unroll
                for (int j = 0; j < 4; ++j) o_acc[qf][nf][j] *= sc[j];
        }
        // P -> LDS (transpose to MFMA-A layout). row=query, col=key, XOR swizzle.
        #pragma unroll
        for (int qf = 0; qf < 2; ++qf)
            #pragma unroll
            for (int kf = 0; kf < 4; ++kf) {
                unsigned short u[4] = {f2bf(sacc[kf][qf][0]), f2bf(sacc[kf][qf][1]),
                                       f2bf(sacc[kf][qf][2]), f2bf(sacc[kf][qf][3])};
                const int row = qf*16 + r0;
                const int byte = (row*128 + kf*32 + q4*8) ^ ((row & 7) << 4);
                *(uint2*)((char*)P + byte) = *(const uint2*)u;
            }
        // PV: O[q,d] += P[q,k] * Vt[d,k]
        #pragma unroll
        for (int c = 0; c < 2; ++c) {
            bf16x8 pa[2];
            #pragma unroll
            for (int qf = 0; qf < 2; ++qf) {
                const int row = qf*16 + r0;
                const int byte = (row*128 + c*64 + q4*16) ^ ((row & 7) << 4);
                pa[qf] = *(const bf16x8*)((char*)P + byte);
            }
            bf16x8 vb[8];
            #pragma unroll
            for (int nf = 0; nf < 8; ++nf)
                vb[nf] = *(const bf16x8*)&Vp[(long long)(nf*16 + r0)*S_LEN + kv + c*32 + q4*8];
            #pragma unroll
            for (int nf = 0; nf < 8; ++nf)
                #pragma unroll
                for (int qf = 0; qf < 2; ++qf)
                    o_acc[qf][nf] = __builtin_amdgcn_mfma_f32_16x16x32_bf16(
                        pa[qf], vb[nf], o_acc[qf][nf], 0, 0, 0);
        }
    }
    // normalize + store
    #pragma unroll
    for (int qf = 0; qf < 2; ++qf) {
        const float inv = 1.f / l_[qf];
        float iv[4];
        #pragma unroll
        for (int j = 0; j < 4; ++j) iv[j] = __shfl(inv, (q4*4 + j) | (lane & 48));
        #pragma unroll
        for (int nf = 0; nf < 8; ++nf)
            #pragma unroll
            for (int j = 0; j < 4; ++j) {
                const int grow = qt*128 + wid*32 + qf*16 + q4*4 + j;
                O[base + (long long)grow*HD + nf*16 + r0] = f2bf(o_acc[qf][nf][j] * iv[j]);
            }
    }
}

// x (NB,E,S) f32 -> xT (NB,S,E) bf16
__global__ __launch_bounds__(256) void transpose_conv(
    const float* __restrict__ x, unsigned short* __restrict__ xT)
{
    __shared__ float t[32][33];
    const int n = blockIdx.z;
    const int e0 = blockIdx.y * 32, s0 = blockIdx.x * 32;
    const int tx = threadIdx.x & 31, ty = threadIdx.x >> 5;
    #pragma unroll
    for (int i = 0; i < 4; ++i) {
        const int e = ty + i*8;
        t[e][tx] = x[((long long)n*E_DIM + e0 + e)*S_LEN + s0 + tx];
    }
    __syncthreads();
    #pragma unroll
    for (int i = 0; i < 4; ++i) {
        const int s = ty + i*8;
        xT[((long long)n*S_LEN + s0 + s)*E_DIM + e0 + tx] = f2bf(t[tx][s]);
    }
}

__global__ __launch_bounds__(256) void conv_bf16(
    const float* __restrict__ in, unsigned short* __restrict__ out, int n8)
{
    const int i = blockIdx.x * 256 + threadIdx.x;
    if (i >= n8) return;
    const float4 a = ((const float4*)in)[2*i];
    const float4 b = ((const float4*)in)[2*i + 1];
    unsigned short u[8] = {f2bf(a.x), f2bf(a.y), f2bf(a.z), f2bf(a.w),
                           f2bf(b.x), f2bf(b.y), f2bf(b.z), f2bf(b.w)};
    ((uint4*)out)[i] = *(const uint4*)u;
}

extern "C" void kernel_launch(void* const* d_in, const int* in_sizes, int n_in,
                              void* d_out, int out_size, void* d_ws, size_t ws_size,
                              hipStream_t stream)
{
    const float* x   = (const float*)d_in[0];
    const float* W_r = (const float*)d_in[1];
    const float* b_r = (const float*)d_in[2];
    const float* Wq  = (const float*)d_in[3];
    const float* bq  = (const float*)d_in[4];
    const float* Wk  = (const float*)d_in[5];
    const float* bk  = (const float*)d_in[6];
    const float* Wv  = (const float*)d_in[7];
    const float* bv  = (const float*)d_in[8];
    const float* Wo  = (const float*)d_in[9];
    const float* bo  = (const float*)d_in[10];
    float* out = (float*)d_out;
    (void)in_sizes; (void)n_in; (void)out_size; (void)ws_size;

    char* w = (char*)d_ws;
    size_t off = 0;
    auto take = [&](size_t bytes) -> unsigned short* {
        unsigned short* p = (unsigned short*)(w + off);
        off = (off + bytes + 255) & ~(size_t)255;
        return p;
    };
    unsigned short* Wr_b = take((size_t)S_LEN*E_DIM*2);
    unsigned short* xT_b = take((size_t)NB*S_LEN*E_DIM*2);
    unsigned short* Wq_b = take((size_t)NH*HD*HD*2);
    unsigned short* Wk_b = take((size_t)NH*HD*HD*2);
    unsigned short* Wv_b = take((size_t)NH*HD*HD*2);
    unsigned short* Wo_b = take((size_t)E_DIM*S_LEN*2);
    unsigned short* Rd_b = take((size_t)NB*S_LEN*S_LEN*2);   // reduced (n,j,s) bf16
    unsigned short* Q_b  = take((size_t)NPAIR*S_LEN*HD*2);   // (h,n,s,d)
    unsigned short* K_b  = take((size_t)NPAIR*S_LEN*HD*2);   // (h,n,s,d)
    unsigned short* Vt_b = take((size_t)NPAIR*HD*S_LEN*2);   // (h,n,d,t)  V^T
    unsigned short* O_b  = take((size_t)NPAIR*S_LEN*HD*2);   // (h,n,s,d) = reshape view

    conv_bf16<<<dim3((S_LEN*E_DIM/8 + 255)/256), 256, 0, stream>>>(W_r, Wr_b, S_LEN*E_DIM/8);
    conv_bf16<<<dim3((NH*HD*HD/8 + 255)/256), 256, 0, stream>>>(Wq, Wq_b, NH*HD*HD/8);
    conv_bf16<<<dim3((NH*HD*HD/8 + 255)/256), 256, 0, stream>>>(Wk, Wk_b, NH*HD*HD/8);
    conv_bf16<<<dim3((NH*HD*HD/8 + 255)/256), 256, 0, stream>>>(Wv, Wv_b, NH*HD*HD/8);
    conv_bf16<<<dim3((E_DIM*S_LEN/8 + 255)/256), 256, 0, stream>>>(Wo, Wo_b, E_DIM*S_LEN/8);
    transpose_conv<<<dim3(S_LEN/32, E_DIM/32, NB), 256, 0, stream>>>(x, xT_b);

    // reduced[n,j,s] = W_r @ x[n]^T + b_r[j]
    gemm_bt<0,1><<<dim3(S_LEN/128, S_LEN/128, NB), 256, 0, stream>>>(
        Wr_b, xT_b, Rd_b, b_r, nullptr,
        E_DIM, E_DIM, E_DIM, S_LEN, 1,
        0LL, 0LL, (long long)S_LEN*E_DIM, 0LL, (long long)S_LEN*S_LEN, 0LL, 0, 0);

    // Q/K projections: z=(h,n)
    gemm_bt<0,1><<<dim3(HD/128, S_LEN/128, NPAIR), 256, 0, stream>>>(
        Rd_b, Wq_b, Q_b, nullptr, bq,
        HD, S_LEN, HD, HD, NB,
        128LL, (long long)S_LEN*S_LEN, (long long)HD*HD, 0LL,
        (long long)NB*S_LEN*HD, (long long)S_LEN*HD, 0, HD);
    gemm_bt<0,1><<<dim3(HD/128, S_LEN/128, NPAIR), 256, 0, stream>>>(
        Rd_b, Wk_b, K_b, nullptr, bk,
        HD, S_LEN, HD, HD, NB,
        128LL, (long long)S_LEN*S_LEN, (long long)HD*HD, 0LL,
        (long long)NB*S_LEN*HD, (long long)S_LEN*HD, 0, HD);
    // V produced transposed: Vt = Wv_h @ R^T
    gemm_bt<0,1><<<dim3(S_LEN/128, HD/128, NPAIR), 256, 0, stream>>>(
        Wv_b, Rd_b, Vt_b, bv, nullptr,
        HD, HD, S_LEN, S_LEN, NB,
        (long long)HD*HD, 0LL, 128LL, (long long)S_LEN*S_LEN,
        (long long)NB*HD*S_LEN, (long long)HD*S_LEN, HD, 0);

    // fused attention
    flash_attn<<<dim3(S_LEN/128, NPAIR), 256, 0, stream>>>(Q_b, K_b, Vt_b, O_b);

    // out[n] = O_resh[n] @ Wo^T + bo
    gemm_bt<1,1><<<dim3(E_DIM/128, S_LEN/128, NB), 256, 0, stream>>>(
        O_b, Wo_b, out, nullptr, bo,
        S_LEN, S_LEN, S_LEN, E_DIM, 1,
        (long long)S_LEN*S_LEN, 0LL, 0LL, 0LL, (long long)S_LEN*E_DIM, 0LL, 0, 0);
}

// Round 3
// 303.988 us; speedup vs baseline: 1.4783x; 1.4490x over previous
//
#include <hip/hip_runtime.h>

#define S_LEN 2048
#define E_DIM 1024
#define NH 16
#define HD 128
#define NB 2
#define NPAIR (NH*NB)

typedef __attribute__((ext_vector_type(4))) float f32x4;
typedef __attribute__((ext_vector_type(8))) short bf16x8;

__device__ __forceinline__ unsigned short f2bf(float f) {
    unsigned u = __builtin_bit_cast(unsigned, f);
    u += 0x7fffu + ((u >> 16) & 1u);
    return (unsigned short)(u >> 16);
}
__device__ __forceinline__ float bf2f(unsigned short h) {
    unsigned u = ((unsigned)h) << 16;
    return __builtin_bit_cast(float, u);
}

__device__ __forceinline__ void gl_lds16(const unsigned short* g, unsigned short* l) {
    __builtin_amdgcn_global_load_lds((__attribute__((address_space(1))) void*)g,
                                     (__attribute__((address_space(3))) void*)l,
                                     16, 0, 0);
}

// C[M,N] = A[M,K] @ B[N,K]^T (+bias_row +bias_col), bf16 in, fp32 acc.
// 2-phase double-buffered (stage t+1 before compute t, ONE barrier/iter).
// SWZ=1: XCD-chunked block swizzle on the full flattened grid (needs nwg%8==0).
template<int OF32, int SWZ>
__global__ __launch_bounds__(256, 2) void gemm_bt(
    const unsigned short* __restrict__ A, const unsigned short* __restrict__ B,
    void* __restrict__ C,
    const float* __restrict__ brow, const float* __restrict__ bcol,
    int K, int lda, int ldb, int ldc, int zdiv,
    long long a_sh, long long a_sl, long long b_sh, long long b_sl,
    long long c_sh, long long c_sl, int brs, int bcs)
{
    __shared__ unsigned short As[2][128*64];
    __shared__ unsigned short Bs[2][128*64];
    int bm, bn, z;
    if (SWZ) {
        const int gx = gridDim.x, gy = gridDim.y;
        const int nxy = gx * gy;
        const int nwg = nxy * gridDim.z;
        const int flat = (blockIdx.z*gy + blockIdx.y)*gx + blockIdx.x;
        const int id2 = (flat & 7)*(nwg >> 3) + (flat >> 3);
        z = id2 / nxy; const int r = id2 % nxy; bm = r / gx; bn = r % gx;
    } else { bm = blockIdx.y; bn = blockIdx.x; z = blockIdx.z; }
    const int zh = z / zdiv, zl = z % zdiv;
    A += (long long)zh*a_sh + (long long)zl*a_sl;
    B += (long long)zh*b_sh + (long long)zl*b_sl;
    const long long coff = (long long)zh*c_sh + (long long)zl*c_sl;
    const int tid = threadIdx.x, wid = tid >> 6, lane = tid & 63;
    const int l3 = lane >> 3;
    const int cg = (lane & 7) ^ l3;
    const unsigned short* Ag = A + (long long)(bm*128 + wid*32 + l3)*lda + cg*8;
    const unsigned short* Bg = B + (long long)(bn*128 + wid*32 + l3)*ldb + cg*8;

    f32x4 acc[4][4];
    #pragma unroll
    for (int m = 0; m < 4; ++m)
        #pragma unroll
        for (int n = 0; n < 4; ++n)
            #pragma unroll
            for (int j = 0; j < 4; ++j) acc[m][n][j] = 0.f;

    const int r0 = lane & 15, q = lane >> 4;
    const int wr = (wid >> 1) * 64, wc = (wid & 1) * 64;

    auto stage = [&](int buf, int kt) {
        unsigned short* as = &As[buf][wid*32*64];
        unsigned short* bs = &Bs[buf][wid*32*64];
        #pragma unroll
        for (int i = 0; i < 4; ++i) {
            gl_lds16(Ag + (long long)(i*8)*lda + kt, as + i*8*64);
            gl_lds16(Bg + (long long)(i*8)*ldb + kt, bs + i*8*64);
        }
    };

    const int nt = K >> 6;
    stage(0, 0);
    __syncthreads();
    int cur = 0;
    for (int t = 0; t < nt; ++t) {
        if (t + 1 < nt) stage(cur ^ 1, (t + 1) << 6);
        #pragma unroll
        for (int ks = 0; ks < 2; ++ks) {
            bf16x8 av[4], bv[4];
            #pragma unroll
            for (int m = 0; m < 4; ++m) {
                const int ra = wr + m*16 + r0;
                av[m] = *(const bf16x8*)&As[cur][ra*64 + (((ks*4 + q) ^ (ra & 7)) << 3)];
                const int rb = wc + m*16 + r0;
                bv[m] = *(const bf16x8*)&Bs[cur][rb*64 + (((ks*4 + q) ^ (rb & 7)) << 3)];
            }
            __builtin_amdgcn_s_setprio(1);
            #pragma unroll
            for (int m = 0; m < 4; ++m)
                #pragma unroll
                for (int n = 0; n < 4; ++n)
                    acc[m][n] = __builtin_amdgcn_mfma_f32_16x16x32_bf16(
                        av[m], bv[n], acc[m][n], 0, 0, 0);
            __builtin_amdgcn_s_setprio(0);
        }
        __syncthreads();
        cur ^= 1;
    }

    const int rq = lane >> 4;
    const bool has_br = (brow != nullptr), has_bc = (bcol != nullptr);
    #pragma unroll
    for (int m = 0; m < 4; ++m) {
        #pragma unroll
        for (int n = 0; n < 4; ++n) {
            const int gcol = bn*128 + wc + n*16 + r0;
            float cb = has_bc ? bcol[(long long)bcs*zh + gcol] : 0.f;
            #pragma unroll
            for (int j = 0; j < 4; ++j) {
                const int grow = bm*128 + wr + m*16 + rq*4 + j;
                float v = acc[m][n][j] + cb;
                if (has_br) v += brow[(long long)brs*zh + grow];
                const long long idx = coff + (long long)grow*ldc + gcol;
                if (OF32) ((float*)C)[idx] = v;
                else      ((unsigned short*)C)[idx] = f2bf(v);
            }
        }
    }
}

// Fused flash attention: P = softmax(Q K^T), O = P V. No 1/sqrt(d) scaling.
// grid (S/128, NPAIR), 256 thr, 4 waves x 32 q-rows. K/V tiles staged ONCE per
// block into double-buffered LDS (global_load_lds, both-sides XOR swizzle),
// 2-phase pipeline: stage(t+1) issued before compute(t), one barrier/tile.
__global__ __launch_bounds__(256, 2) void flash_attn(
    const unsigned short* __restrict__ Q,    // (pair, s, d)
    const unsigned short* __restrict__ Kb,   // (pair, s, d)
    const unsigned short* __restrict__ Vt,   // (pair, d, t)
    unsigned short* __restrict__ O)          // (pair, s, d)
{
    __shared__ unsigned short Ks[2][64*128];   // 2 x 16KB, row=key, 256B/row
    __shared__ unsigned short Vs[2][128*64];   // 2 x 16KB, row=d,   128B/row
    __shared__ unsigned short Plds[4][32*64];  // 16KB, per-wave P buffer
    const int flat = blockIdx.y * gridDim.x + blockIdx.x;   // nwg = 512
    const int id2 = (flat & 7)*64 + (flat >> 3);            // XCD-chunked
    const int pair = id2 >> 4, qt = id2 & 15;
    const int tid = threadIdx.x, wid = tid >> 6, lane = tid & 63;
    const int r0 = lane & 15, q4 = lane >> 4;
    const long long base = (long long)pair * S_LEN * HD;
    const unsigned short* Qp = Q + base + (long long)(qt*128 + wid*32) * HD;
    const unsigned short* Kp = Kb + base;
    const unsigned short* Vp = Vt + base;
    unsigned short* P = &Plds[wid][0];

    // staging lane geometry (pre-swizzled GLOBAL source, linear LDS dest)
    const int krow = wid*16 + (lane >> 4);          // +i*4 per issue
    const int kc0  = (lane & 15) ^ (lane >> 4);     // ^((i&1)<<2) per issue
    const int vrow = wid*32 + (lane >> 3);          // +i*8 per issue
    const int vc0  = (lane & 7) ^ (lane >> 3);

    auto stageK = [&](int buf, int kv) {
        #pragma unroll
        for (int i = 0; i < 4; ++i)
            gl_lds16(Kp + (long long)(kv + krow + i*4)*HD + ((kc0 ^ ((i & 1) << 2))*8),
                     &Ks[buf][(wid*16 + i*4)*128]);
    };
    auto stageV = [&](int buf, int kv) {
        #pragma unroll
        for (int i = 0; i < 4; ++i)
            gl_lds16(Vp + (long long)(vrow + i*8)*S_LEN + kv + vc0*8,
                     &Vs[buf][(wid*32 + i*8)*64]);
    };

    // Q fragments: row = qf*16 + r0, k-chunk = ks*32 + q4*8
    bf16x8 qfr[2][4];
    #pragma unroll
    for (int qf = 0; qf < 2; ++qf)
        #pragma unroll
        for (int ks = 0; ks < 4; ++ks)
            qfr[qf][ks] = *(const bf16x8*)&Qp[(qf*16 + r0)*HD + ks*32 + q4*8];

    f32x4 o_acc[2][8];
    #pragma unroll
    for (int qf = 0; qf < 2; ++qf)
        #pragma unroll
        for (int nf = 0; nf < 8; ++nf)
            #pragma unroll
            for (int j = 0; j < 4; ++j) o_acc[qf][nf][j] = 0.f;
    float m_[2] = {-3.0e38f, -3.0e38f}, l_[2] = {0.f, 0.f};

    stageK(0, 0); stageV(0, 0);
    __syncthreads();
    int cur = 0;
    for (int kv = 0; kv < S_LEN; kv += 64) {
        if (kv + 64 < S_LEN) { stageK(cur ^ 1, kv + 64); stageV(cur ^ 1, kv + 64); }
        // ---- S^T tile: mfma(K, Q) -> row=key, col=query(lane&15) ----
        f32x4 sacc[4][2];
        #pragma unroll
        for (int kf = 0; kf < 4; ++kf)
            #pragma unroll
            for (int qf = 0; qf < 2; ++qf)
                #pragma unroll
                for (int j = 0; j < 4; ++j) sacc[kf][qf][j] = 0.f;
        #pragma unroll
        for (int ks = 0; ks < 4; ++ks) {
            bf16x8 kfr[4];
            #pragma unroll
            for (int kf = 0; kf < 4; ++kf) {
                const int row = kf*16 + r0;
                kfr[kf] = *(const bf16x8*)&Ks[cur][row*128 + (((ks*4 + q4) ^ (r0 & 7)) << 3)];
            }
            __builtin_amdgcn_s_setprio(1);
            #pragma unroll
            for (int kf = 0; kf < 4; ++kf)
                #pragma unroll
                for (int qf = 0; qf < 2; ++qf)
                    sacc[kf][qf] = __builtin_amdgcn_mfma_f32_16x16x32_bf16(
                        kfr[kf], qfr[qf][ks], sacc[kf][qf], 0, 0, 0);
            __builtin_amdgcn_s_setprio(0);
        }
        // ---- online softmax; lane's column = query qf*16+r0 ----
        #pragma unroll
        for (int qf = 0; qf < 2; ++qf) {
            float tmax = -3.0e38f;
            #pragma unroll
            for (int kf = 0; kf < 4; ++kf)
                #pragma unroll
                for (int j = 0; j < 4; ++j) tmax = fmaxf(tmax, sacc[kf][qf][j]);
            tmax = fmaxf(tmax, __shfl_xor(tmax, 16));
            tmax = fmaxf(tmax, __shfl_xor(tmax, 32));
            const float mnew = fmaxf(m_[qf], tmax);
            const float scale = __expf(m_[qf] - mnew);
            float tsum = 0.f;
            #pragma unroll
            for (int kf = 0; kf < 4; ++kf)
                #pragma unroll
                for (int j = 0; j < 4; ++j) {
                    const float e = __expf(sacc[kf][qf][j] - mnew);
                    sacc[kf][qf][j] = e; tsum += e;
                }
            tsum += __shfl_xor(tsum, 16);
            tsum += __shfl_xor(tsum, 32);
            l_[qf] = l_[qf]*scale + tsum;
            m_[qf] = mnew;
            float sc[4];
            #pragma unroll
            for (int j = 0; j < 4; ++j) sc[j] = __shfl(scale, (q4*4 + j) | (lane & 48));
            #pragma unroll
            for (int nf = 0; nf < 8; ++nf)
                #pragma unroll
                for (int j = 0; j < 4; ++j) o_acc[qf][nf][j] *= sc[j];
        }
        // ---- P -> per-wave LDS (transpose to MFMA-A layout), XOR swizzle ----
        #pragma unroll
        for (int qf = 0; qf < 2; ++qf)
            #pragma unroll
            for (int kf = 0; kf < 4; ++kf) {
                unsigned short u[4] = {f2bf(sacc[kf][qf][0]), f2bf(sacc[kf][qf][1]),
                                       f2bf(sacc[kf][qf][2]), f2bf(sacc[kf][qf][3])};
                const int row = qf*16 + r0;
                const int byte = (row*128 + kf*32 + q4*8) ^ ((row & 7) << 4);
                *(uint2*)((char*)P + byte) = *(const uint2*)u;
            }
        // ---- PV: O[q,d] += P[q,k] * Vt[d,k] ----
        #pragma unroll
        for (int c = 0; c < 2; ++c) {
            bf16x8 pa[2];
            #pragma unroll
            for (int qf = 0; qf < 2; ++qf) {
                const int row = qf*16 + r0;
                const int byte = (row*128 + c*64 + q4*16) ^ ((row & 7) << 4);
                pa[qf] = *(const bf16x8*)((char*)P + byte);
            }
            bf16x8 vb[8];
            #pragma unroll
            for (int nf = 0; nf < 8; ++nf) {
                const int row = nf*16 + r0;
                vb[nf] = *(const bf16x8*)&Vs[cur][row*64 + (((c*4 + q4) ^ (r0 & 7)) << 3)];
            }
            __builtin_amdgcn_s_setprio(1);
            #pragma unroll
            for (int nf = 0; nf < 8; ++nf)
                #pragma unroll
                for (int qf = 0; qf < 2; ++qf)
                    o_acc[qf][nf] = __builtin_amdgcn_mfma_f32_16x16x32_bf16(
                        pa[qf], vb[nf], o_acc[qf][nf], 0, 0, 0);
            __builtin_amdgcn_s_setprio(0);
        }
        __syncthreads();   // drains stage(t+1) loads + WAR fence on cur
        cur ^= 1;
    }
    // ---- normalize + store ----
    #pragma unroll
    for (int qf = 0; qf < 2; ++qf) {
        const float inv = 1.f / l_[qf];
        float iv[4];
        #pragma unroll
        for (int j = 0; j < 4; ++j) iv[j] = __shfl(inv, (q4*4 + j) | (lane & 48));
        #pragma unroll
        for (int nf = 0; nf < 8; ++nf)
            #pragma unroll
            for (int j = 0; j < 4; ++j) {
                const int grow = qt*128 + wid*32 + qf*16 + q4*4 + j;
                O[base + (long long)grow*HD + nf*16 + r0] = f2bf(o_acc[qf][nf][j] * iv[j]);
            }
    }
}

// x (NB,E,S) f32 -> xT (NB,S,E) bf16
__global__ __launch_bounds__(256) void transpose_conv(
    const float* __restrict__ x, unsigned short* __restrict__ xT)
{
    __shared__ float t[32][33];
    const int n = blockIdx.z;
    const int e0 = blockIdx.y * 32, s0 = blockIdx.x * 32;
    const int tx = threadIdx.x & 31, ty = threadIdx.x >> 5;
    #pragma unroll
    for (int i = 0; i < 4; ++i) {
        const int e = ty + i*8;
        t[e][tx] = x[((long long)n*E_DIM + e0 + e)*S_LEN + s0 + tx];
    }
    __syncthreads();
    #pragma unroll
    for (int i = 0; i < 4; ++i) {
        const int s = ty + i*8;
        xT[((long long)n*S_LEN + s0 + s)*E_DIM + e0 + tx] = f2bf(t[tx][s]);
    }
}

__global__ __launch_bounds__(256) void conv_bf16(
    const float* __restrict__ in, unsigned short* __restrict__ out, int n8)
{
    const int i = blockIdx.x * 256 + threadIdx.x;
    if (i >= n8) return;
    const float4 a = ((const float4*)in)[2*i];
    const float4 b = ((const float4*)in)[2*i + 1];
    unsigned short u[8] = {f2bf(a.x), f2bf(a.y), f2bf(a.z), f2bf(a.w),
                           f2bf(b.x), f2bf(b.y), f2bf(b.z), f2bf(b.w)};
    ((uint4*)out)[i] = *(const uint4*)u;
}

extern "C" void kernel_launch(void* const* d_in, const int* in_sizes, int n_in,
                              void* d_out, int out_size, void* d_ws, size_t ws_size,
                              hipStream_t stream)
{
    const float* x   = (const float*)d_in[0];
    const float* W_r = (const float*)d_in[1];
    const float* b_r = (const float*)d_in[2];
    const float* Wq  = (const float*)d_in[3];
    const float* bq  = (const float*)d_in[4];
    const float* Wk  = (const float*)d_in[5];
    const float* bk  = (const float*)d_in[6];
    const float* Wv  = (const float*)d_in[7];
    const float* bv  = (const float*)d_in[8];
    const float* Wo  = (const float*)d_in[9];
    const float* bo  = (const float*)d_in[10];
    float* out = (float*)d_out;
    (void)in_sizes; (void)n_in; (void)out_size; (void)ws_size;

    char* w = (char*)d_ws;
    size_t off = 0;
    auto take = [&](size_t bytes) -> unsigned short* {
        unsigned short* p = (unsigned short*)(w + off);
        off = (off + bytes + 255) & ~(size_t)255;
        return p;
    };
    unsigned short* Wr_b = take((size_t)S_LEN*E_DIM*2);
    unsigned short* xT_b = take((size_t)NB*S_LEN*E_DIM*2);
    unsigned short* Wq_b = take((size_t)NH*HD*HD*2);
    unsigned short* Wk_b = take((size_t)NH*HD*HD*2);
    unsigned short* Wv_b = take((size_t)NH*HD*HD*2);
    unsigned short* Wo_b = take((size_t)E_DIM*S_LEN*2);
    unsigned short* Rd_b = take((size_t)NB*S_LEN*S_LEN*2);   // reduced (n,j,s) bf16
    unsigned short* Q_b  = take((size_t)NPAIR*S_LEN*HD*2);   // (h,n,s,d)
    unsigned short* K_b  = take((size_t)NPAIR*S_LEN*HD*2);   // (h,n,s,d)
    unsigned short* Vt_b = take((size_t)NPAIR*HD*S_LEN*2);   // (h,n,d,t)  V^T
    unsigned short* O_b  = take((size_t)NPAIR*S_LEN*HD*2);   // (h,n,s,d) = reshape view

    conv_bf16<<<dim3((S_LEN*E_DIM/8 + 255)/256), 256, 0, stream>>>(W_r, Wr_b, S_LEN*E_DIM/8);
    conv_bf16<<<dim3((NH*HD*HD/8 + 255)/256), 256, 0, stream>>>(Wq, Wq_b, NH*HD*HD/8);
    conv_bf16<<<dim3((NH*HD*HD/8 + 255)/256), 256, 0, stream>>>(Wk, Wk_b, NH*HD*HD/8);
    conv_bf16<<<dim3((NH*HD*HD/8 + 255)/256), 256, 0, stream>>>(Wv, Wv_b, NH*HD*HD/8);
    conv_bf16<<<dim3((E_DIM*S_LEN/8 + 255)/256), 256, 0, stream>>>(Wo, Wo_b, E_DIM*S_LEN/8);
    transpose_conv<<<dim3(S_LEN/32, E_DIM/32, NB), 256, 0, stream>>>(x, xT_b);

    // reduced[n,j,s] = W_r @ x[n]^T + b_r[j]
    gemm_bt<0,1><<<dim3(S_LEN/128, S_LEN/128, NB), 256, 0, stream>>>(
        Wr_b, xT_b, Rd_b, b_r, nullptr,
        E_DIM, E_DIM, E_DIM, S_LEN, 1,
        0LL, 0LL, (long long)S_LEN*E_DIM, 0LL, (long long)S_LEN*S_LEN, 0LL, 0, 0);

    // Q/K projections: z=(h,n)
    gemm_bt<0,1><<<dim3(HD/128, S_LEN/128, NPAIR), 256, 0, stream>>>(
        Rd_b, Wq_b, Q_b, nullptr, bq,
        HD, S_LEN, HD, HD, NB,
        128LL, (long long)S_LEN*S_LEN, (long long)HD*HD, 0LL,
        (long long)NB*S_LEN*HD, (long long)S_LEN*HD, 0, HD);
    gemm_bt<0,1><<<dim3(HD/128, S_LEN/128, NPAIR), 256, 0, stream>>>(
        Rd_b, Wk_b, K_b, nullptr, bk,
        HD, S_LEN, HD, HD, NB,
        128LL, (long long)S_LEN*S_LEN, (long long)HD*HD, 0LL,
        (long long)NB*S_LEN*HD, (long long)S_LEN*HD, 0, HD);
    // V produced transposed: Vt = Wv_h @ R^T
    gemm_bt<0,1><<<dim3(S_LEN/128, HD/128, NPAIR), 256, 0, stream>>>(
        Wv_b, Rd_b, Vt_b, bv, nullptr,
        HD, HD, S_LEN, S_LEN, NB,
        (long long)HD*HD, 0LL, 128LL, (long long)S_LEN*S_LEN,
        (long long)NB*HD*S_LEN, (long long)HD*S_LEN, HD, 0);

    // fused attention
    flash_attn<<<dim3(S_LEN/128, NPAIR), 256, 0, stream>>>(Q_b, K_b, Vt_b, O_b);

    // out[n] = O_resh[n] @ Wo^T + bo
    gemm_bt<1,1><<<dim3(E_DIM/128, S_LEN/128, NB), 256, 0, stream>>>(
        O_b, Wo_b, out, nullptr, bo,
        S_LEN, S_LEN, S_LEN, E_DIM, 1,
        (long long)S_LEN*S_LEN, 0LL, 0LL, 0LL, (long long)S_LEN*E_DIM, 0LL, 0, 0);
}

// Round 5
// 302.340 us; speedup vs baseline: 1.4863x; 1.0055x over previous
//
#include <hip/hip_runtime.h>

#define S_LEN 2048
#define E_DIM 1024
#define NH 16
#define HD 128
#define NB 2
#define NPAIR (NH*NB)

typedef __attribute__((ext_vector_type(4))) float f32x4;
typedef __attribute__((ext_vector_type(8))) short bf16x8;

__device__ __forceinline__ unsigned short f2bf(float f) {
    unsigned u = __builtin_bit_cast(unsigned, f);
    u += 0x7fffu + ((u >> 16) & 1u);
    return (unsigned short)(u >> 16);
}
__device__ __forceinline__ float bf2f(unsigned short h) {
    unsigned u = ((unsigned)h) << 16;
    return __builtin_bit_cast(float, u);
}
// packed f32x2 -> bf16x2 (RTNE), one VALU inst
__device__ __forceinline__ unsigned cvtpk(float lo, float hi) {
    unsigned r;
    asm("v_cvt_pk_bf16_f32 %0, %1, %2" : "=v"(r) : "v"(lo), "v"(hi));
    return r;
}

__device__ __forceinline__ void gl_lds16(const unsigned short* g, unsigned short* l) {
    __builtin_amdgcn_global_load_lds((__attribute__((address_space(1))) void*)g,
                                     (__attribute__((address_space(3))) void*)l,
                                     16, 0, 0);
}

// C[M,N] = A[M,K] @ B[N,K]^T (+bias_row +bias_col), bf16 in, fp32 acc.
// 2-phase double-buffered (stage t+1 before compute t, ONE barrier/iter).
// SWZ=1: XCD-chunked block swizzle on the full flattened grid (needs nwg%8==0).
template<int OF32, int SWZ>
__global__ __launch_bounds__(256, 2) void gemm_bt(
    const unsigned short* __restrict__ A, const unsigned short* __restrict__ B,
    void* __restrict__ C,
    const float* __restrict__ brow, const float* __restrict__ bcol,
    int K, int lda, int ldb, int ldc, int zdiv,
    long long a_sh, long long a_sl, long long b_sh, long long b_sl,
    long long c_sh, long long c_sl, int brs, int bcs)
{
    __shared__ unsigned short As[2][128*64];
    __shared__ unsigned short Bs[2][128*64];
    int bm, bn, z;
    if (SWZ) {
        const int gx = gridDim.x, gy = gridDim.y;
        const int nxy = gx * gy;
        const int nwg = nxy * gridDim.z;
        const int flat = (blockIdx.z*gy + blockIdx.y)*gx + blockIdx.x;
        const int id2 = (flat & 7)*(nwg >> 3) + (flat >> 3);
        z = id2 / nxy; const int r = id2 % nxy; bm = r / gx; bn = r % gx;
    } else { bm = blockIdx.y; bn = blockIdx.x; z = blockIdx.z; }
    const int zh = z / zdiv, zl = z % zdiv;
    A += (long long)zh*a_sh + (long long)zl*a_sl;
    B += (long long)zh*b_sh + (long long)zl*b_sl;
    const long long coff = (long long)zh*c_sh + (long long)zl*c_sl;
    const int tid = threadIdx.x, wid = tid >> 6, lane = tid & 63;
    const int l3 = lane >> 3;
    const int cg = (lane & 7) ^ l3;
    const unsigned short* Ag = A + (long long)(bm*128 + wid*32 + l3)*lda + cg*8;
    const unsigned short* Bg = B + (long long)(bn*128 + wid*32 + l3)*ldb + cg*8;

    f32x4 acc[4][4];
    #pragma unroll
    for (int m = 0; m < 4; ++m)
        #pragma unroll
        for (int n = 0; n < 4; ++n)
            #pragma unroll
            for (int j = 0; j < 4; ++j) acc[m][n][j] = 0.f;

    const int r0 = lane & 15, q = lane >> 4;
    const int wr = (wid >> 1) * 64, wc = (wid & 1) * 64;

    auto stage = [&](int buf, int kt) {
        unsigned short* as = &As[buf][wid*32*64];
        unsigned short* bs = &Bs[buf][wid*32*64];
        #pragma unroll
        for (int i = 0; i < 4; ++i) {
            gl_lds16(Ag + (long long)(i*8)*lda + kt, as + i*8*64);
            gl_lds16(Bg + (long long)(i*8)*ldb + kt, bs + i*8*64);
        }
    };

    const int nt = K >> 6;
    stage(0, 0);
    __syncthreads();
    int cur = 0;
    for (int t = 0; t < nt; ++t) {
        if (t + 1 < nt) stage(cur ^ 1, (t + 1) << 6);
        #pragma unroll
        for (int ks = 0; ks < 2; ++ks) {
            bf16x8 av[4], bv[4];
            #pragma unroll
            for (int m = 0; m < 4; ++m) {
                const int ra = wr + m*16 + r0;
                av[m] = *(const bf16x8*)&As[cur][ra*64 + (((ks*4 + q) ^ (ra & 7)) << 3)];
                const int rb = wc + m*16 + r0;
                bv[m] = *(const bf16x8*)&Bs[cur][rb*64 + (((ks*4 + q) ^ (rb & 7)) << 3)];
            }
            __builtin_amdgcn_s_setprio(1);
            #pragma unroll
            for (int m = 0; m < 4; ++m)
                #pragma unroll
                for (int n = 0; n < 4; ++n)
                    acc[m][n] = __builtin_amdgcn_mfma_f32_16x16x32_bf16(
                        av[m], bv[n], acc[m][n], 0, 0, 0);
            __builtin_amdgcn_s_setprio(0);
        }
        __syncthreads();
        cur ^= 1;
    }

    const int rq = lane >> 4;
    const bool has_br = (brow != nullptr), has_bc = (bcol != nullptr);
    #pragma unroll
    for (int m = 0; m < 4; ++m) {
        #pragma unroll
        for (int n = 0; n < 4; ++n) {
            const int gcol = bn*128 + wc + n*16 + r0;
            float cb = has_bc ? bcol[(long long)bcs*zh + gcol] : 0.f;
            #pragma unroll
            for (int j = 0; j < 4; ++j) {
                const int grow = bm*128 + wr + m*16 + rq*4 + j;
                float v = acc[m][n][j] + cb;
                if (has_br) v += brow[(long long)brs*zh + grow];
                const long long idx = coff + (long long)grow*ldc + gcol;
                if (OF32) ((float*)C)[idx] = v;
                else      ((unsigned short*)C)[idx] = f2bf(v);
            }
        }
    }
}

// Fused flash attention: P = softmax(Q K^T), O = P V. No 1/sqrt(d) scaling.
// grid (S/128, NPAIR), 256 thr, 4 waves x 32 q-rows. K/V tiles double-buffered
// in LDS (global_load_lds, both-sides XOR swizzle), 2-phase pipeline.
// VALU diet: defer-max THR=8 (T13), cvt_pk P-pack (T12), max3 tree (T17).
__global__ __launch_bounds__(256, 2) void flash_attn(
    const unsigned short* __restrict__ Q,    // (pair, s, d)
    const unsigned short* __restrict__ Kb,   // (pair, s, d)
    const unsigned short* __restrict__ Vt,   // (pair, d, t)
    unsigned short* __restrict__ O)          // (pair, s, d)
{
    __shared__ unsigned short Ks[2][64*128];   // 2 x 16KB, row=key
    __shared__ unsigned short Vs[2][128*64];   // 2 x 16KB, row=d
    __shared__ unsigned short Plds[4][32*64];  // 16KB, per-wave P buffer
    const int flat = blockIdx.y * gridDim.x + blockIdx.x;   // nwg = 512
    const int id2 = (flat & 7)*64 + (flat >> 3);            // XCD-chunked
    const int pair = id2 >> 4, qt = id2 & 15;
    const int tid = threadIdx.x, wid = tid >> 6, lane = tid & 63;
    const int r0 = lane & 15, q4 = lane >> 4;
    const long long base = (long long)pair * S_LEN * HD;
    const unsigned short* Qp = Q + base + (long long)(qt*128 + wid*32) * HD;
    const unsigned short* Kp = Kb + base;
    const unsigned short* Vp = Vt + base;
    unsigned short* P = &Plds[wid][0];

    const int krow = wid*16 + (lane >> 4);
    const int kc0  = (lane & 15) ^ (lane >> 4);
    const int vrow = wid*32 + (lane >> 3);
    const int vc0  = (lane & 7) ^ (lane >> 3);

    auto stageK = [&](int buf, int kv) {
        #pragma unroll
        for (int i = 0; i < 4; ++i)
            gl_lds16(Kp + (long long)(kv + krow + i*4)*HD + ((kc0 ^ ((i & 1) << 2))*8),
                     &Ks[buf][(wid*16 + i*4)*128]);
    };
    auto stageV = [&](int buf, int kv) {
        #pragma unroll
        for (int i = 0; i < 4; ++i)
            gl_lds16(Vp + (long long)(vrow + i*8)*S_LEN + kv + vc0*8,
                     &Vs[buf][(wid*32 + i*8)*64]);
    };

    bf16x8 qfr[2][4];
    #pragma unroll
    for (int qf = 0; qf < 2; ++qf)
        #pragma unroll
        for (int ks = 0; ks < 4; ++ks)
            qfr[qf][ks] = *(const bf16x8*)&Qp[(qf*16 + r0)*HD + ks*32 + q4*8];

    f32x4 o_acc[2][8];
    #pragma unroll
    for (int qf = 0; qf < 2; ++qf)
        #pragma unroll
        for (int nf = 0; nf < 8; ++nf)
            #pragma unroll
            for (int j = 0; j < 4; ++j) o_acc[qf][nf][j] = 0.f;
    float m_[2] = {-3.0e38f, -3.0e38f}, l_[2] = {0.f, 0.f};

    stageK(0, 0); stageV(0, 0);
    __syncthreads();
    int cur = 0;
    for (int kv = 0; kv < S_LEN; kv += 64) {
        if (kv + 64 < S_LEN) { stageK(cur ^ 1, kv + 64); stageV(cur ^ 1, kv + 64); }
        // ---- S^T tile: mfma(K, Q) -> row=key, col=query(lane&15) ----
        f32x4 sacc[4][2];
        #pragma unroll
        for (int kf = 0; kf < 4; ++kf)
            #pragma unroll
            for (int qf = 0; qf < 2; ++qf)
                #pragma unroll
                for (int j = 0; j < 4; ++j) sacc[kf][qf][j] = 0.f;
        #pragma unroll
        for (int ks = 0; ks < 4; ++ks) {
            bf16x8 kfr[4];
            #pragma unroll
            for (int kf = 0; kf < 4; ++kf) {
                const int row = kf*16 + r0;
                kfr[kf] = *(const bf16x8*)&Ks[cur][row*128 + (((ks*4 + q4) ^ (r0 & 7)) << 3)];
            }
            __builtin_amdgcn_s_setprio(1);
            #pragma unroll
            for (int kf = 0; kf < 4; ++kf)
                #pragma unroll
                for (int qf = 0; qf < 2; ++qf)
                    sacc[kf][qf] = __builtin_amdgcn_mfma_f32_16x16x32_bf16(
                        kfr[kf], qfr[qf][ks], sacc[kf][qf], 0, 0, 0);
            __builtin_amdgcn_s_setprio(0);
        }
        // ---- online softmax; lane's column = query qf*16+r0 ----
        #pragma unroll
        for (int qf = 0; qf < 2; ++qf) {
            // max3-tree row max (clang fuses nested fmaxf to v_max3_f32)
            float t0 = fmaxf(fmaxf(sacc[0][qf][0], sacc[0][qf][1]),
                             fmaxf(sacc[0][qf][2], sacc[0][qf][3]));
            float t1 = fmaxf(fmaxf(sacc[1][qf][0], sacc[1][qf][1]),
                             fmaxf(sacc[1][qf][2], sacc[1][qf][3]));
            float t2 = fmaxf(fmaxf(sacc[2][qf][0], sacc[2][qf][1]),
                             fmaxf(sacc[2][qf][2], sacc[2][qf][3]));
            float t3 = fmaxf(fmaxf(sacc[3][qf][0], sacc[3][qf][1]),
                             fmaxf(sacc[3][qf][2], sacc[3][qf][3]));
            float tmax = fmaxf(fmaxf(t0, t1), fmaxf(t2, t3));
            tmax = fmaxf(tmax, __shfl_xor(tmax, 16));
            tmax = fmaxf(tmax, __shfl_xor(tmax, 32));
            if (__all(tmax <= m_[qf] + 8.f)) {
                // defer-max: keep old m, no rescale (P bounded by e^8)
                float tsum = 0.f;
                #pragma unroll
                for (int kf = 0; kf < 4; ++kf)
                    #pragma unroll
                    for (int j = 0; j < 4; ++j) {
                        const float e = __expf(sacc[kf][qf][j] - m_[qf]);
                        sacc[kf][qf][j] = e; tsum += e;
                    }
                tsum += __shfl_xor(tsum, 16);
                tsum += __shfl_xor(tsum, 32);
                l_[qf] += tsum;
            } else {
                const float mnew = fmaxf(m_[qf], tmax);
                const float scale = __expf(m_[qf] - mnew);
                float tsum = 0.f;
                #pragma unroll
                for (int kf = 0; kf < 4; ++kf)
                    #pragma unroll
                    for (int j = 0; j < 4; ++j) {
                        const float e = __expf(sacc[kf][qf][j] - mnew);
                        sacc[kf][qf][j] = e; tsum += e;
                    }
                tsum += __shfl_xor(tsum, 16);
                tsum += __shfl_xor(tsum, 32);
                l_[qf] = l_[qf]*scale + tsum;
                m_[qf] = mnew;
                float sc[4];
                #pragma unroll
                for (int j = 0; j < 4; ++j) sc[j] = __shfl(scale, (q4*4 + j) | (lane & 48));
                #pragma unroll
                for (int nf = 0; nf < 8; ++nf)
                    #pragma unroll
                    for (int j = 0; j < 4; ++j) o_acc[qf][nf][j] *= sc[j];
            }
        }
        // ---- P -> per-wave LDS (transpose to MFMA-A layout), XOR swizzle ----
        #pragma unroll
        for (int qf = 0; qf < 2; ++qf)
            #pragma unroll
            for (int kf = 0; kf < 4; ++kf) {
                uint2 pk;
                pk.x = cvtpk(sacc[kf][qf][0], sacc[kf][qf][1]);
                pk.y = cvtpk(sacc[kf][qf][2], sacc[kf][qf][3]);
                const int row = qf*16 + r0;
                const int byte = (row*128 + kf*32 + q4*8) ^ ((row & 7) << 4);
                *(uint2*)((char*)P + byte) = pk;
            }
        // ---- PV: O[q,d] += P[q,k] * Vt[d,k] ----
        #pragma unroll
        for (int c = 0; c < 2; ++c) {
            bf16x8 pa[2];
            #pragma unroll
            for (int qf = 0; qf < 2; ++qf) {
                const int row = qf*16 + r0;
                const int byte = (row*128 + c*64 + q4*16) ^ ((row & 7) << 4);
                pa[qf] = *(const bf16x8*)((char*)P + byte);
            }
            bf16x8 vb[8];
            #pragma unroll
            for (int nf = 0; nf < 8; ++nf) {
                const int row = nf*16 + r0;
                vb[nf] = *(const bf16x8*)&Vs[cur][row*64 + (((c*4 + q4) ^ (r0 & 7)) << 3)];
            }
            __builtin_amdgcn_s_setprio(1);
            #pragma unroll
            for (int nf = 0; nf < 8; ++nf)
                #pragma unroll
                for (int qf = 0; qf < 2; ++qf)
                    o_acc[qf][nf] = __builtin_amdgcn_mfma_f32_16x16x32_bf16(
                        pa[qf], vb[nf], o_acc[qf][nf], 0, 0, 0);
            __builtin_amdgcn_s_setprio(0);
        }
        __syncthreads();
        cur ^= 1;
    }
    // ---- normalize + store ----
    #pragma unroll
    for (int qf = 0; qf < 2; ++qf) {
        const float inv = 1.f / l_[qf];
        float iv[4];
        #pragma unroll
        for (int j = 0; j < 4; ++j) iv[j] = __shfl(inv, (q4*4 + j) | (lane & 48));
        #pragma unroll
        for (int nf = 0; nf < 8; ++nf)
            #pragma unroll
            for (int j = 0; j < 4; ++j) {
                const int grow = qt*128 + wid*32 + qf*16 + q4*4 + j;
                O[base + (long long)grow*HD + nf*16 + r0] = f2bf(o_acc[qf][nf][j] * iv[j]);
            }
    }
}

// x (NB,E,S) f32 -> xT (NB,S,E) bf16
__global__ __launch_bounds__(256) void transpose_conv(
    const float* __restrict__ x, unsigned short* __restrict__ xT)
{
    __shared__ float t[32][33];
    const int n = blockIdx.z;
    const int e0 = blockIdx.y * 32, s0 = blockIdx.x * 32;
    const int tx = threadIdx.x & 31, ty = threadIdx.x >> 5;
    #pragma unroll
    for (int i = 0; i < 4; ++i) {
        const int e = ty + i*8;
        t[e][tx] = x[((long long)n*E_DIM + e0 + e)*S_LEN + s0 + tx];
    }
    __syncthreads();
    #pragma unroll
    for (int i = 0; i < 4; ++i) {
        const int s = ty + i*8;
        xT[((long long)n*S_LEN + s0 + s)*E_DIM + e0 + tx] = f2bf(t[tx][s]);
    }
}

__global__ __launch_bounds__(256) void conv_bf16(
    const float* __restrict__ in, unsigned short* __restrict__ out, int n8)
{
    const int i = blockIdx.x * 256 + threadIdx.x;
    if (i >= n8) return;
    const float4 a = ((const float4*)in)[2*i];
    const float4 b = ((const float4*)in)[2*i + 1];
    unsigned short u[8] = {f2bf(a.x), f2bf(a.y), f2bf(a.z), f2bf(a.w),
                           f2bf(b.x), f2bf(b.y), f2bf(b.z), f2bf(b.w)};
    ((uint4*)out)[i] = *(const uint4*)u;
}

extern "C" void kernel_launch(void* const* d_in, const int* in_sizes, int n_in,
                              void* d_out, int out_size, void* d_ws, size_t ws_size,
                              hipStream_t stream)
{
    const float* x   = (const float*)d_in[0];
    const float* W_r = (const float*)d_in[1];
    const float* b_r = (const float*)d_in[2];
    const float* Wq  = (const float*)d_in[3];
    const float* bq  = (const float*)d_in[4];
    const float* Wk  = (const float*)d_in[5];
    const float* bk  = (const float*)d_in[6];
    const float* Wv  = (const float*)d_in[7];
    const float* bv  = (const float*)d_in[8];
    const float* Wo  = (const float*)d_in[9];
    const float* bo  = (const float*)d_in[10];
    float* out = (float*)d_out;
    (void)in_sizes; (void)n_in; (void)out_size; (void)ws_size;

    char* w = (char*)d_ws;
    size_t off = 0;
    auto take = [&](size_t bytes) -> unsigned short* {
        unsigned short* p = (unsigned short*)(w + off);
        off = (off + bytes + 255) & ~(size_t)255;
        return p;
    };
    unsigned short* Wr_b = take((size_t)S_LEN*E_DIM*2);
    unsigned short* xT_b = take((size_t)NB*S_LEN*E_DIM*2);
    unsigned short* Wq_b = take((size_t)NH*HD*HD*2);
    unsigned short* Wk_b = take((size_t)NH*HD*HD*2);
    unsigned short* Wv_b = take((size_t)NH*HD*HD*2);
    unsigned short* Wo_b = take((size_t)E_DIM*S_LEN*2);
    unsigned short* Rd_b = take((size_t)NB*S_LEN*S_LEN*2);   // reduced (n,j,s) bf16
    unsigned short* Q_b  = take((size_t)NPAIR*S_LEN*HD*2);   // (h,n,s,d)
    unsigned short* K_b  = take((size_t)NPAIR*S_LEN*HD*2);   // (h,n,s,d)
    unsigned short* Vt_b = take((size_t)NPAIR*HD*S_LEN*2);   // (h,n,d,t)  V^T
    unsigned short* O_b  = take((size_t)NPAIR*S_LEN*HD*2);   // (h,n,s,d) = reshape view

    conv_bf16<<<dim3((S_LEN*E_DIM/8 + 255)/256), 256, 0, stream>>>(W_r, Wr_b, S_LEN*E_DIM/8);
    conv_bf16<<<dim3((NH*HD*HD/8 + 255)/256), 256, 0, stream>>>(Wq, Wq_b, NH*HD*HD/8);
    conv_bf16<<<dim3((NH*HD*HD/8 + 255)/256), 256, 0, stream>>>(Wk, Wk_b, NH*HD*HD/8);
    conv_bf16<<<dim3((NH*HD*HD/8 + 255)/256), 256, 0, stream>>>(Wv, Wv_b, NH*HD*HD/8);
    conv_bf16<<<dim3((E_DIM*S_LEN/8 + 255)/256), 256, 0, stream>>>(Wo, Wo_b, E_DIM*S_LEN/8);
    transpose_conv<<<dim3(S_LEN/32, E_DIM/32, NB), 256, 0, stream>>>(x, xT_b);

    // reduced[n,j,s] = W_r @ x[n]^T + b_r[j]
    gemm_bt<0,1><<<dim3(S_LEN/128, S_LEN/128, NB), 256, 0, stream>>>(
        Wr_b, xT_b, Rd_b, b_r, nullptr,
        E_DIM, E_DIM, E_DIM, S_LEN, 1,
        0LL, 0LL, (long long)S_LEN*E_DIM, 0LL, (long long)S_LEN*S_LEN, 0LL, 0, 0);

    // Q/K projections: z=(h,n)
    gemm_bt<0,1><<<dim3(HD/128, S_LEN/128, NPAIR), 256, 0, stream>>>(
        Rd_b, Wq_b, Q_b, nullptr, bq,
        HD, S_LEN, HD, HD, NB,
        128LL, (long long)S_LEN*S_LEN, (long long)HD*HD, 0LL,
        (long long)NB*S_LEN*HD, (long long)S_LEN*HD, 0, HD);
    gemm_bt<0,1><<<dim3(HD/128, S_LEN/128, NPAIR), 256, 0, stream>>>(
        Rd_b, Wk_b, K_b, nullptr, bk,
        HD, S_LEN, HD, HD, NB,
        128LL, (long long)S_LEN*S_LEN, (long long)HD*HD, 0LL,
        (long long)NB*S_LEN*HD, (long long)S_LEN*HD, 0, HD);
    // V produced transposed: Vt = Wv_h @ R^T
    gemm_bt<0,1><<<dim3(S_LEN/128, HD/128, NPAIR), 256, 0, stream>>>(
        Wv_b, Rd_b, Vt_b, bv, nullptr,
        HD, HD, S_LEN, S_LEN, NB,
        (long long)HD*HD, 0LL, 128LL, (long long)S_LEN*S_LEN,
        (long long)NB*HD*S_LEN, (long long)HD*S_LEN, HD, 0);

    // fused attention
    flash_attn<<<dim3(S_LEN/128, NPAIR), 256, 0, stream>>>(Q_b, K_b, Vt_b, O_b);

    // out[n] = O_resh[n] @ Wo^T + bo
    gemm_bt<1,1><<<dim3(E_DIM/128, S_LEN/128, NB), 256, 0, stream>>>(
        O_b, Wo_b, out, nullptr, bo,
        S_LEN, S_LEN, S_LEN, E_DIM, 1,
        (long long)S_LEN*S_LEN, 0LL, 0LL, 0LL, (long long)S_LEN*E_DIM, 0LL, 0, 0);
}